// Round 1
// baseline (410.166 us; speedup 1.0000x reference)
//
#include <hip/hip_runtime.h>

// TemporalXORReservoirNetwork: 200-step leaky-integrate-and-fire reservoir.
// Batch rows are independent => 1 block per batch element, no grid sync.
// V lives in registers (2 neurons/thread), S[b,:] as a 2048-bit mask in LDS.
// Expected dynamics: no spikes (threshold is ~8 sigma above V distribution),
// so the S@W sparse gather is gated off by a cumulative spike counter and the
// kernel is bound by the 419 MB spk_rec write stream.

#define SEQ    200
#define BATCH  256
#define NRES   2048
#define NTHR   1024
#define BETA_F 0.9f

__global__ __launch_bounds__(NTHR, 1) void snn_reservoir_kernel(
    const float* __restrict__ x,     // [200, 256, 3]
    const float* __restrict__ W,     // [2048, 2048]  (row k -> col n)
    const float* __restrict__ Win,   // [2048, 3]
    const float* __restrict__ Wout,  // [2, 2048]
    float* __restrict__ out)         // spk_rec [200,256,2048] then logits [256,2]
{
    const int b    = blockIdx.x;
    const int tid  = threadIdx.x;
    const int lane = tid & 63;
    const int wid  = tid >> 6;        // 16 waves
    const int n0   = tid << 1;        // this thread owns neurons n0, n0+1

    // Double-buffered spike bitmask: wave w writes words 2w (even n) / 2w+1 (odd n).
    // Bit l of word 2w   -> n = 128*w + 2*l
    // Bit l of word 2w+1 -> n = 128*w + 2*l + 1
    __shared__ unsigned long long smask[2][32];
    __shared__ int   scum[2];         // cumulative spike count per parity (never reset)
    __shared__ float4 sx[SEQ];        // x[:, b, :] staged once
    __shared__ float red[2][16];

    for (int t = tid; t < SEQ; t += NTHR) {
        const float* p = x + (size_t)t * (BATCH * 3) + b * 3;
        sx[t] = make_float4(p[0], p[1], p[2], 0.0f);
    }
    if (tid < 64) smask[tid >> 5][tid & 31] = 0ull;
    if (tid < 2)  scum[tid] = 0;

    // Per-thread input weights (persist in registers for all 200 steps)
    const float* wr = Win + (size_t)n0 * 3;
    const float w00 = wr[0], w01 = wr[1], w02 = wr[2];
    const float w10 = wr[3], w11 = wr[4], w12 = wr[5];

    float V0 = 0.f, V1 = 0.f;
    int cnt0 = 0, cnt1 = 0;

    __syncthreads();   // full barrier once: staging loads + LDS init visible

    auto step = [&](int t, int cur, int prev, int& seen) {
        float rec0 = 0.f, rec1 = 0.f;
        const int c = scum[prev];
        if (__builtin_expect(c != seen, 0)) {
            // spikes occurred at step t-1: sparse gather of W rows
            seen = c;
            #pragma unroll 1
            for (int u = 0; u < 32; ++u) {
                unsigned long long m = smask[prev][u];
                const int kbase = ((u >> 1) << 7) + (u & 1);
                while (m) {
                    const int l = __builtin_ctzll(m);
                    m &= m - 1;
                    const int k = kbase + (l << 1);
                    const float2 wv = *(const float2*)(W + (size_t)k * NRES + n0);
                    rec0 += wv.x;
                    rec1 += wv.y;
                }
            }
        }
        const float4 xv = sx[t];
        const float i0 = fmaf(xv.x, w00, fmaf(xv.y, w01, xv.z * w02)) + rec0;
        const float i1 = fmaf(xv.x, w10, fmaf(xv.y, w11, xv.z * w12)) + rec1;
        V0 = fmaf(BETA_F, V0, i0);
        V1 = fmaf(BETA_F, V1, i1);
        const bool s0 = (V0 >= 1.0f);
        const bool s1 = (V1 >= 1.0f);
        V0 = s0 ? 0.f : V0;
        V1 = s1 ? 0.f : V1;
        *(float2*)(out + ((size_t)t * BATCH + b) * NRES + n0) =
            make_float2(s0 ? 1.f : 0.f, s1 ? 1.f : 0.f);
        if (t >= SEQ - 10) { cnt0 += (int)s0; cnt1 += (int)s1; }
        const unsigned long long b0 = __ballot(s0);
        const unsigned long long b1 = __ballot(s1);
        if (lane == 0) {
            smask[cur][2 * wid]     = b0;
            smask[cur][2 * wid + 1] = b1;
            const int pc = __popcll(b0) + __popcll(b1);
            if (pc) atomicAdd(&scum[cur], pc);
        }
        // LDS-only barrier: __syncthreads() would emit s_waitcnt vmcnt(0) and
        // drain the spk_rec store stream every step (~800 cy). Only LDS
        // ordering (lgkmcnt) is required for smask/scum correctness.
        asm volatile("s_waitcnt lgkmcnt(0)\n\ts_barrier" ::: "memory");
    };

    int seen0 = 0, seen1 = 0;
    for (int tt = 0; tt < SEQ; tt += 2) {
        step(tt,     0, 1, seen1);   // even t: cur=0, prev=1
        step(tt + 1, 1, 0, seen0);   // odd  t: cur=1, prev=0
    }

    // logits[b, o] = sum_n (cnt[n]/10) * Wout[o, n]
    const float a0 = (float)cnt0 * 0.1f;
    const float a1 = (float)cnt1 * 0.1f;
    float p0 = fmaf(a0, Wout[n0], a1 * Wout[n0 + 1]);
    float p1 = fmaf(a0, Wout[NRES + n0], a1 * Wout[NRES + n0 + 1]);
    #pragma unroll
    for (int off = 32; off > 0; off >>= 1) {
        p0 += __shfl_down(p0, off);
        p1 += __shfl_down(p1, off);
    }
    if (lane == 0) { red[0][wid] = p0; red[1][wid] = p1; }
    __syncthreads();
    if (tid == 0) {
        float q0 = 0.f, q1 = 0.f;
        #pragma unroll
        for (int i = 0; i < 16; ++i) { q0 += red[0][i]; q1 += red[1][i]; }
        const size_t loff = (size_t)SEQ * BATCH * NRES;
        out[loff + b * 2 + 0] = q0;
        out[loff + b * 2 + 1] = q1;
    }
}

extern "C" void kernel_launch(void* const* d_in, const int* in_sizes, int n_in,
                              void* d_out, int out_size, void* d_ws, size_t ws_size,
                              hipStream_t stream) {
    const float* x    = (const float*)d_in[0];
    const float* W    = (const float*)d_in[1];
    const float* Win  = (const float*)d_in[2];
    const float* Wout = (const float*)d_in[3];
    float* out = (float*)d_out;
    hipLaunchKernelGGL(snn_reservoir_kernel, dim3(BATCH), dim3(NTHR), 0, stream,
                       x, W, Win, Wout, out);
}